// Round 5
// baseline (1554.379 us; speedup 1.0000x reference)
//
#include <hip/hip_runtime.h>
#include <cstddef>
#include <cstdint>

// ---------------------------------------------------------------------------
// SAGE_89429809037918: pre-Linear(128->128) -> SAGEConv(128->256)+ReLU
//   -> SAGEConv(256->256)+ReLU -> SAGEConv(256->256) -> row L2-normalize.
// R10: R9 with compile fix (__builtin_nontemporal_store needs ext_vector
//      type, not HIP uint4 struct). R9 theory: bucket-sweep persistent
//      gather. R8 post-mortem: 64B slices drag 128B lines -> per-XCD working
//      set 6.4MB > 4MB L2; space-partitioning dead. R7 regime: 214MB
//      random-line misses @~3.3TB/s is the binding path. Fix: sweep src
//      table in 8 contiguous 6250-node buckets (3.2MB fits XCD L2).
//      Persistent kernel (768 blocks), acc in VGPRs across sweep, edges
//      sorted by (dst, src-bucket). Timeout-bounded atomic barrier between
//      buckets (locality hint only; correctness independent).
// ---------------------------------------------------------------------------

typedef __attribute__((ext_vector_type(8))) short short8;   // 8 bf16 = 4 VGPR
typedef __attribute__((ext_vector_type(4))) float f32x4;
typedef __attribute__((ext_vector_type(4))) unsigned int u32x4;

__device__ __forceinline__ unsigned rne_bf16(float f) {
    unsigned b = __float_as_uint(f);
    return (b + 0x7fffu + ((b >> 16) & 1u)) >> 16;
}
__device__ __forceinline__ float bf16_lo(unsigned u) { return __uint_as_float(u << 16); }
__device__ __forceinline__ float bf16_hi(unsigned u) { return __uint_as_float(u & 0xffff0000u); }

#define NBUK 8
#define BUCKN 6250u

// ---------------- 2D counting sort: (dst, src-bucket) ----------------------

__global__ __launch_bounds__(256) void hist2(const int* __restrict__ src,
                                             const int* __restrict__ dst,
                                             int* __restrict__ cnt2, int E) {
    int e = blockIdx.x * 256 + threadIdx.x;
    if (e < E) {
        int key = dst[e] * NBUK + (int)((unsigned)src[e] / BUCKN);
        atomicAdd(&cnt2[key], 1);
    }
}

// per-block exclusive scan + block sums
__global__ __launch_bounds__(256) void scanA(const int* __restrict__ in,
                                             int* __restrict__ out,
                                             int* __restrict__ bsum, int m) {
    int i = blockIdx.x * 256 + threadIdx.x;
    int v = (i < m) ? in[i] : 0;
    int incl = v;
#pragma unroll
    for (int s = 1; s < 64; s <<= 1) {
        int u = __shfl_up(incl, s);
        if ((threadIdx.x & 63) >= s) incl += u;
    }
    __shared__ int ws[4];
    int lane = threadIdx.x & 63, w = threadIdx.x >> 6;
    if (lane == 63) ws[w] = incl;
    __syncthreads();
    int woff = 0;
    for (int j = 0; j < w; ++j) woff += ws[j];
    if (i < m) out[i] = woff + incl - v;
    if (threadIdx.x == 255) bsum[blockIdx.x] = woff + incl;
}

// single-block exclusive scan over nb block sums
__global__ __launch_bounds__(256) void scanB(const int* __restrict__ bsum,
                                             int* __restrict__ boff, int nb) {
    __shared__ int ws[4];
    __shared__ int carry;
    int t = threadIdx.x;
    int lane = t & 63, w = t >> 6;
    if (t == 0) carry = 0;
    __syncthreads();
    for (int base = 0; base < nb; base += 256) {
        int i = base + t;
        int v = (i < nb) ? bsum[i] : 0;
        int incl = v;
#pragma unroll
        for (int s = 1; s < 64; s <<= 1) {
            int u = __shfl_up(incl, s);
            if (lane >= s) incl += u;
        }
        if (lane == 63) ws[w] = incl;
        __syncthreads();
        int woff = 0;
        for (int j = 0; j < w; ++j) woff += ws[j];
        int c = carry;
        if (i < nb) boff[i] = c + woff + incl - v;
        __syncthreads();
        if (t == 255) carry = c + woff + incl;
        __syncthreads();
    }
}

__global__ __launch_bounds__(256) void scanC(int* __restrict__ out,
                                             const int* __restrict__ boff,
                                             int m, int E) {
    int i = blockIdx.x * 256 + threadIdx.x;
    if (i < m) out[i] += boff[i >> 8];
    if (i == 0) out[m] = E;
}

__global__ __launch_bounds__(256) void invk(const int* __restrict__ off2,
                                            float* __restrict__ inv, int n) {
    int d = blockIdx.x * 256 + threadIdx.x;
    if (d < n) {
        int a = off2[d * NBUK], b = off2[d * NBUK + NBUK];
        inv[d] = 1.0f / fmaxf((float)(b - a), 1.0f);
    }
}

__global__ __launch_bounds__(256) void fill2(const int* __restrict__ src,
                                             const int* __restrict__ dst,
                                             const int* __restrict__ off2,
                                             int* __restrict__ cnt2,
                                             unsigned short* __restrict__ ssrc16,
                                             int E) {
    int e = blockIdx.x * 256 + threadIdx.x;
    if (e >= E) return;
    int s = src[e];
    int key = dst[e] * NBUK + (int)((unsigned)s / BUCKN);
    int pos = off2[key] + atomicSub(&cnt2[key], 1) - 1;
    ssrc16[pos] = (unsigned short)s;
}

// ---------------- one-shot converts: x -> bf16, W -> bf16 transposed --------

__global__ __launch_bounds__(256) void xconv(const float* __restrict__ x,
                                             uint2* __restrict__ xb, int n4) {
    int i = blockIdx.x * 256 + threadIdx.x;
    if (i >= n4) return;
    float4 v = ((const float4*)x)[i];
    uint2 o;
    o.x = rne_bf16(v.x) | (rne_bf16(v.y) << 16);
    o.y = rne_bf16(v.z) | (rne_bf16(v.w) << 16);
    xb[i] = o;
}

// W [K][Nn] fp32 -> WT [Nn][K] bf16, for all 7 weight matrices in one launch
__global__ __launch_bounds__(256) void wprep(
    const float* __restrict__ pre_W, const float* __restrict__ W1_l,
    const float* __restrict__ W1_r, const float* __restrict__ W2_l,
    const float* __restrict__ W2_r, const float* __restrict__ W3_l,
    const float* __restrict__ W3_r,
    unsigned short* __restrict__ WT0, unsigned short* __restrict__ WT1,
    unsigned short* __restrict__ WT2, unsigned short* __restrict__ WT3,
    unsigned short* __restrict__ WT4, unsigned short* __restrict__ WT5,
    unsigned short* __restrict__ WT6) {
    int idx = blockIdx.x * 256 + threadIdx.x;
    if (idx < 16384) {  // pre_W 128x128
        int k = idx >> 7, n = idx & 127;
        WT0[n * 128 + k] = (unsigned short)rne_bf16(pre_W[idx]);
        return;
    }
    idx -= 16384;
    if (idx < 32768) {  // W1_l 128x256
        int k = idx >> 8, n = idx & 255;
        WT1[n * 128 + k] = (unsigned short)rne_bf16(W1_l[idx]);
        return;
    }
    idx -= 32768;
    if (idx < 32768) {  // W1_r 128x256
        int k = idx >> 8, n = idx & 255;
        WT2[n * 128 + k] = (unsigned short)rne_bf16(W1_r[idx]);
        return;
    }
    idx -= 32768;
    if (idx < 65536) {  // W2_l 256x256
        int k = idx >> 8, n = idx & 255;
        WT3[n * 256 + k] = (unsigned short)rne_bf16(W2_l[idx]);
        return;
    }
    idx -= 65536;
    if (idx < 65536) {  // W2_r
        int k = idx >> 8, n = idx & 255;
        WT4[n * 256 + k] = (unsigned short)rne_bf16(W2_r[idx]);
        return;
    }
    idx -= 65536;
    if (idx < 65536) {  // W3_l
        int k = idx >> 8, n = idx & 255;
        WT5[n * 256 + k] = (unsigned short)rne_bf16(W3_l[idx]);
        return;
    }
    idx -= 65536;
    if (idx < 65536) {  // W3_r
        int k = idx >> 8, n = idx & 255;
        WT6[n * 256 + k] = (unsigned short)rne_bf16(W3_r[idx]);
    }
}

// ---------------- persistent bucket-sweep gather ---------------------------
// 768 blocks x 256 thr (3 blocks/CU, 12 waves/CU resident). Each wave: NPW
// nodes x SLOTS slots, acc in VGPRs across the whole 8-bucket sweep. Edges
// of node n in bucket b: off2[n*8+b .. +1). Bucket working set fits XCD L2.
// Timeout-bounded atomic barrier between buckets: locality hint only.

template <int D>
__global__ __launch_bounds__(256, 3) void gather_p(
    const unsigned short* __restrict__ h, const int* __restrict__ off2,
    const unsigned short* __restrict__ ssrc16, const float* __restrict__ inv,
    unsigned short* __restrict__ agg, int* __restrict__ bar, int n) {
    constexpr int LPN = D / 8;                   // lanes covering one row
    constexpr int NPW = 64 / LPN;                // nodes per wave per slot
    constexpr int PASS = 768 * 4 * NPW;          // nodes per slot-pass
    constexpr int SLOTS = (50000 + PASS - 1) / PASS;  // 9 (D=256) / 5 (D=128)

    const int t = threadIdx.x;
    const int lane = t & 63;
    const int gw = blockIdx.x * 4 + (t >> 6);
    const int part = lane / LPN;
    const int sub = lane % LPN;                  // 16B chunk within row
    const int nb0 = gw * NPW + part;

    float acc[SLOTS][8];
#pragma unroll
    for (int s = 0; s < SLOTS; ++s)
#pragma unroll
        for (int i = 0; i < 8; ++i) acc[s][i] = 0.f;

    for (int b = 0; b < NBUK; ++b) {
#pragma unroll
        for (int s = 0; s < SLOTS; ++s) {
            int node = nb0 + s * PASS;
            if (node < n) {
                int k = off2[node * NBUK + b];
                int k1 = off2[node * NBUK + b + 1];
                for (; k + 1 < k1; k += 2) {     // 2 rows in flight per group
                    unsigned s0 = __builtin_nontemporal_load(&ssrc16[k]);
                    unsigned s1 = __builtin_nontemporal_load(&ssrc16[k + 1]);
                    uint4 u = *(const uint4*)(h + (size_t)s0 * D + sub * 8);
                    uint4 v = *(const uint4*)(h + (size_t)s1 * D + sub * 8);
                    acc[s][0] += bf16_lo(u.x) + bf16_lo(v.x);
                    acc[s][1] += bf16_hi(u.x) + bf16_hi(v.x);
                    acc[s][2] += bf16_lo(u.y) + bf16_lo(v.y);
                    acc[s][3] += bf16_hi(u.y) + bf16_hi(v.y);
                    acc[s][4] += bf16_lo(u.z) + bf16_lo(v.z);
                    acc[s][5] += bf16_hi(u.z) + bf16_hi(v.z);
                    acc[s][6] += bf16_lo(u.w) + bf16_lo(v.w);
                    acc[s][7] += bf16_hi(u.w) + bf16_hi(v.w);
                }
                if (k < k1) {
                    unsigned s0 = __builtin_nontemporal_load(&ssrc16[k]);
                    uint4 u = *(const uint4*)(h + (size_t)s0 * D + sub * 8);
                    acc[s][0] += bf16_lo(u.x); acc[s][1] += bf16_hi(u.x);
                    acc[s][2] += bf16_lo(u.y); acc[s][3] += bf16_hi(u.y);
                    acc[s][4] += bf16_lo(u.z); acc[s][5] += bf16_hi(u.z);
                    acc[s][6] += bf16_lo(u.w); acc[s][7] += bf16_hi(u.w);
                }
            }
        }
        if (b != NBUK - 1) {                     // locality barrier (bounded)
            __syncthreads();
            if (t == 0) {
                atomicAdd(&bar[b], 1);
                int spins = 0;
                while (atomicAdd(&bar[b], 0) < (int)gridDim.x && spins < 2000) {
                    __builtin_amdgcn_s_sleep(16);
                    ++spins;
                }
            }
            __syncthreads();
        }
    }

#pragma unroll
    for (int s = 0; s < SLOTS; ++s) {
        int node = nb0 + s * PASS;
        if (node < n) {
            float sc = inv[node];
            u32x4 o;
            o.x = rne_bf16(acc[s][0] * sc) | (rne_bf16(acc[s][1] * sc) << 16);
            o.y = rne_bf16(acc[s][2] * sc) | (rne_bf16(acc[s][3] * sc) << 16);
            o.z = rne_bf16(acc[s][4] * sc) | (rne_bf16(acc[s][5] * sc) << 16);
            o.w = rne_bf16(acc[s][6] * sc) | (rne_bf16(acc[s][7] * sc) << 16);
            __builtin_nontemporal_store(
                o, (u32x4*)(agg + (size_t)node * D + sub * 8));
        }
    }
}

// ---------------- MFMA GEMM: out = act(A1@W1T^T + bias + A2@W2T^T) ---------
// A row-major bf16 [M,K]; WT row-major bf16 [Nn,K] (i.e. W transposed).
// Block tile 128x128, 4 waves 2x2 (64x64/wave = 4x4 frags of 16x16), BK=64.
// LDS slots XOR-swizzled (LDS slot s of row r holds global chunk s^(r&7))
// so ds_read_b128 on the fragment side is <=2-way bank-aliased (free).
__global__ __launch_bounds__(256) void gemm_bt(
    const unsigned short* __restrict__ A1, const unsigned short* __restrict__ W1T,
    const unsigned short* __restrict__ A2, const unsigned short* __restrict__ W2T,
    const float* __restrict__ bias,
    unsigned short* __restrict__ outb, float* __restrict__ outf,
    int M, int K, int Nn, int relu) {
    __shared__ __align__(16) unsigned short As[128 * 64];
    __shared__ __align__(16) unsigned short Bs[128 * 64];

    const int t = threadIdx.x;
    const int lane = t & 63;
    const int w = t >> 6;
    const int wm = w >> 1, wn = w & 1;
    const int m0 = blockIdx.x * 128;
    const int n0 = blockIdx.y * 128;

    f32x4 acc[4][4];
#pragma unroll
    for (int i = 0; i < 4; ++i)
#pragma unroll
        for (int j = 0; j < 4; ++j) acc[i][j] = (f32x4){0.f, 0.f, 0.f, 0.f};

    for (int pass = 0; pass < 2; ++pass) {
        const unsigned short* A = pass ? A2 : A1;
        const unsigned short* W = pass ? W2T : W1T;
        if (pass && A2 == nullptr) break;

        for (int k0 = 0; k0 < K; k0 += 64) {
            // stage 128x64 A-tile and B-tile: each thread moves 4x 16B chunks
#pragma unroll
            for (int r = 0; r < 4; ++r) {
                int p = r * 256 + t;          // LDS 16B-chunk index 0..1023
                int row = p >> 3, slot = p & 7;
                int c = slot ^ (row & 7);     // which global chunk lands here
                int gm = m0 + row;
                if (gm >= M) gm = M - 1;      // clamp; result rows >=M discarded
                uint4 va = *(const uint4*)(A + (size_t)gm * K + k0 + c * 8);
                uint4 vb = *(const uint4*)(W + (size_t)(n0 + row) * K + k0 + c * 8);
                *(uint4*)&As[(size_t)p * 8] = va;
                *(uint4*)&Bs[(size_t)p * 8] = vb;
            }
            __syncthreads();
#pragma unroll
            for (int kk = 0; kk < 2; ++kk) {
                short8 af[4], bfr[4];
                int ac = kk * 4 + (lane >> 4);
#pragma unroll
                for (int i = 0; i < 4; ++i) {
                    int arow = wm * 64 + i * 16 + (lane & 15);
                    af[i] = *(const short8*)&As[arow * 64 + ((ac ^ (arow & 7)) << 3)];
                    int brow = wn * 64 + i * 16 + (lane & 15);
                    bfr[i] = *(const short8*)&Bs[brow * 64 + ((ac ^ (brow & 7)) << 3)];
                }
#pragma unroll
                for (int mi = 0; mi < 4; ++mi)
#pragma unroll
                    for (int ni = 0; ni < 4; ++ni)
                        acc[mi][ni] = __builtin_amdgcn_mfma_f32_16x16x32_bf16(
                            af[mi], bfr[ni], acc[mi][ni], 0, 0, 0);
            }
            __syncthreads();
        }
    }

    // epilogue: C/D layout col(n)=lane&15, row(m)=(lane>>4)*4+reg
#pragma unroll
    for (int ni = 0; ni < 4; ++ni) {
        int n = n0 + wn * 64 + ni * 16 + (lane & 15);
        float bv = (bias != nullptr) ? bias[n] : 0.0f;
#pragma unroll
        for (int mi = 0; mi < 4; ++mi) {
            int mbase = m0 + wm * 64 + mi * 16 + ((lane >> 4) << 2);
#pragma unroll
            for (int r = 0; r < 4; ++r) {
                int m = mbase + r;
                if (m >= M) continue;
                float v = acc[mi][ni][r] + bv;
                if (relu) v = fmaxf(v, 0.0f);
                if (outb) outb[(size_t)m * Nn + n] = (unsigned short)rne_bf16(v);
                else      outf[(size_t)m * Nn + n] = v;
            }
        }
    }
}

// row-wise L2 normalize, rows of 256 floats; 4 rows per 256-thread block
__global__ __launch_bounds__(256) void norm_kernel(float* __restrict__ out, int M) {
    int row  = blockIdx.x * 4 + (threadIdx.x >> 6);
    int lane = threadIdx.x & 63;
    if (row >= M) return;
    float4 v = *(float4*)(out + (size_t)row * 256 + (lane << 2));
    float s = v.x * v.x + v.y * v.y + v.z * v.z + v.w * v.w;
#pragma unroll
    for (int off = 32; off > 0; off >>= 1) s += __shfl_down(s, off);
    s = __shfl(s, 0);
    float scale = 1.0f / fmaxf(sqrtf(s), 1e-12f);
    v.x *= scale; v.y *= scale; v.z *= scale; v.w *= scale;
    *(float4*)(out + (size_t)row * 256 + (lane << 2)) = v;
}

extern "C" void kernel_launch(void* const* d_in, const int* in_sizes, int n_in,
                              void* d_out, int out_size, void* d_ws, size_t ws_size,
                              hipStream_t stream) {
    const int N = 50000;
    const int E = 800000;
    const int M2 = N * NBUK;             // 400000 (dst,bucket) keys
    const int NB2 = (M2 + 255) / 256;    // 1563

    const float* x     = (const float*)d_in[0];
    const int*   ei    = (const int*)d_in[1];
    const float* pre_W = (const float*)d_in[2];
    const float* pre_b = (const float*)d_in[3];
    const float* W1_l  = (const float*)d_in[4];
    const float* b1    = (const float*)d_in[5];
    const float* W1_r  = (const float*)d_in[6];
    const float* W2_l  = (const float*)d_in[7];
    const float* b2    = (const float*)d_in[8];
    const float* W2_r  = (const float*)d_in[9];
    const float* W3_l  = (const float*)d_in[10];
    const float* b3    = (const float*)d_in[11];
    const float* W3_r  = (const float*)d_in[12];
    float* out = (float*)d_out;

    const int* src = ei;
    const int* dst = ei + E;

    // ---- workspace layout ----
    int* cnt2  = (int*)d_ws;             // 400000
    int* off2  = cnt2 + M2;              // 400001
    int* bsum2 = off2 + M2 + 1;          // 1568
    int* boff2 = bsum2 + 1568;           // 1568
    int* bar   = boff2 + 1568;           // 32 (3 launches x 8, padded)
    unsigned short* ssrc16 = (unsigned short*)(bar + 32);  // E uint16
    size_t words = (size_t)M2 + (M2 + 1) + 1568 + 1568 + 32 + E / 2;
    words = (words + 3) & ~(size_t)3;    // 16B align

    float* inv = (float*)d_ws + words;
    unsigned short* us = (unsigned short*)(inv + N);

    unsigned short* xb  = us;                 us += (size_t)N * 128;
    unsigned short* WT0 = us;                 us += 16384;
    unsigned short* WT1 = us;                 us += 32768;
    unsigned short* WT2 = us;                 us += 32768;
    unsigned short* WT3 = us;                 us += 65536;
    unsigned short* WT4 = us;                 us += 65536;
    unsigned short* WT5 = us;                 us += 65536;
    unsigned short* WT6 = us;                 us += 65536;
    unsigned short* h0b   = us;               us += (size_t)N * 128;
    unsigned short* agg1b = us;               us += (size_t)N * 128;
    unsigned short* h1b   = us;               us += (size_t)N * 256;
    unsigned short* agg2b = us;               us += (size_t)N * 256;
    unsigned short* h2b   = us;               us += (size_t)N * 256;
    unsigned short* agg3b = us;               us += (size_t)N * 256;

    // ---- build (dst, src-bucket)-segmented CSR ----
    hipMemsetAsync(cnt2, 0, (size_t)M2 * sizeof(int), stream);
    hipMemsetAsync(bar, 0, 32 * sizeof(int), stream);
    hist2<<<(E + 255) / 256, 256, 0, stream>>>(src, dst, cnt2, E);
    scanA<<<NB2, 256, 0, stream>>>(cnt2, off2, bsum2, M2);
    scanB<<<1, 256, 0, stream>>>(bsum2, boff2, NB2);
    scanC<<<NB2, 256, 0, stream>>>(off2, boff2, M2, E);
    invk<<<(N + 255) / 256, 256, 0, stream>>>(off2, inv, N);
    fill2<<<(E + 255) / 256, 256, 0, stream>>>(src, dst, off2, cnt2, ssrc16, E);

    // ---- converts ----
    xconv<<<(N * 128 / 4 + 255) / 256, 256, 0, stream>>>(x, (uint2*)xb, N * 128 / 4);
    wprep<<<(344064 + 255) / 256, 256, 0, stream>>>(pre_W, W1_l, W1_r, W2_l, W2_r,
                                                    W3_l, W3_r, WT0, WT1, WT2, WT3,
                                                    WT4, WT5, WT6);

    const int MT = (N + 127) / 128;  // 391
    const int AG = (N + 3) / 4;

    // ---- pre: h0 = x @ pre_W + pre_b ----
    gemm_bt<<<dim3(MT, 1), 256, 0, stream>>>(xb, WT0, nullptr, nullptr, pre_b,
                                             h0b, nullptr, N, 128, 128, 0);

    // ---- layer 1 ----
    gather_p<128><<<768, 256, 0, stream>>>(h0b, off2, ssrc16, inv, agg1b, bar, N);
    gemm_bt<<<dim3(MT, 2), 256, 0, stream>>>(agg1b, WT1, h0b, WT2, b1,
                                             h1b, nullptr, N, 128, 256, 1);

    // ---- layer 2 ----
    gather_p<256><<<768, 256, 0, stream>>>(h1b, off2, ssrc16, inv, agg2b, bar + 8, N);
    gemm_bt<<<dim3(MT, 2), 256, 0, stream>>>(agg2b, WT3, h1b, WT4, b2,
                                             h2b, nullptr, N, 256, 256, 1);

    // ---- layer 3 (no relu), fp32 straight into d_out ----
    gather_p<256><<<768, 256, 0, stream>>>(h2b, off2, ssrc16, inv, agg3b, bar + 16, N);
    gemm_bt<<<dim3(MT, 2), 256, 0, stream>>>(agg3b, WT5, h2b, WT6, b3,
                                             nullptr, out, N, 256, 256, 0);

    // ---- L2 normalize ----
    norm_kernel<<<AG, 256, 0, stream>>>(out, N);
}

// Round 6
// 497.080 us; speedup vs baseline: 3.1270x; 3.1270x over previous
//
#include <hip/hip_runtime.h>
#include <cstddef>
#include <cstdint>

// ---------------------------------------------------------------------------
// SAGE_89429809037918: pre-Linear(128->128) -> SAGEConv(128->256)+ReLU
//   -> SAGEConv(256->256)+ReLU -> SAGEConv(256->256) -> row L2-normalize.
// R11: revert gather to R7 (best: 65/65/33us; R10 bucket sweep lost 6.5x to
//      per-segment latency despite halved FETCH -> fabric ~6.25TB/s accepted
//      as gather ceiling). Attack the ~330us non-gather residual instead:
//      - gemm_wide: BM=128 BN=256 (A read once, was twice), 512thr 8 waves,
//        global_load_lds(16B) staging with pre-swizzled source + linear LDS
//        dest (m97/m173 pattern), fallback to same-layout VGPR staging.
//      - L2-normalize fused into layer-3 GEMM epilogue (row fully in-block
//        at BN=256): kills the 51MB norm pass + 1 launch.
//      - xconv+wprep merged.
// ---------------------------------------------------------------------------

typedef __attribute__((ext_vector_type(8))) short short8;   // 8 bf16 = 4 VGPR
typedef __attribute__((ext_vector_type(4))) float f32x4;

__device__ __forceinline__ unsigned rne_bf16(float f) {
    unsigned b = __float_as_uint(f);
    return (b + 0x7fffu + ((b >> 16) & 1u)) >> 16;
}
__device__ __forceinline__ float bf16_lo(unsigned u) { return __uint_as_float(u << 16); }
__device__ __forceinline__ float bf16_hi(unsigned u) { return __uint_as_float(u & 0xffff0000u); }

// 16B global->LDS stage. Builtin path: lds base must be wave-uniform, HW adds
// lane*16 (linear dest); source addr is per-lane (carries the swizzle).
__device__ __forceinline__ void stage16(const void* g, unsigned short* ldsbase,
                                        int lane) {
#if __has_builtin(__builtin_amdgcn_global_load_lds)
    (void)lane;
    __builtin_amdgcn_global_load_lds(
        (const __attribute__((address_space(1))) unsigned int*)g,
        (__attribute__((address_space(3))) unsigned int*)ldsbase, 16, 0, 0);
#else
    *(uint4*)(ldsbase + (size_t)lane * 8) = *(const uint4*)g;
#endif
}

// ---------------- counting sort: histogram -> scan -> fill ----------------

__global__ __launch_bounds__(256) void deg_kernel(const int* __restrict__ dst,
                                                  int* __restrict__ deg, int E) {
    int e = blockIdx.x * 256 + threadIdx.x;
    if (e < E) atomicAdd(&deg[dst[e]], 1);
}

__global__ __launch_bounds__(256) void bsum_kernel(const int* __restrict__ deg,
                                                   int* __restrict__ bsum, int n) {
    int i = blockIdx.x * 256 + threadIdx.x;
    int v = (i < n) ? deg[i] : 0;
#pragma unroll
    for (int s = 32; s > 0; s >>= 1) v += __shfl_down(v, s);
    __shared__ int ws[4];
    int lane = threadIdx.x & 63, w = threadIdx.x >> 6;
    if (lane == 0) ws[w] = v;
    __syncthreads();
    if (threadIdx.x == 0) bsum[blockIdx.x] = ws[0] + ws[1] + ws[2] + ws[3];
}

__global__ __launch_bounds__(256) void bscan_kernel(const int* __restrict__ bsum,
                                                    int* __restrict__ boff,
                                                    int* __restrict__ off,
                                                    int nb, int n, int E) {
    int t = threadIdx.x;
    int v = (t < nb) ? bsum[t] : 0;
    int incl = v;
#pragma unroll
    for (int s = 1; s < 64; s <<= 1) {
        int u = __shfl_up(incl, s);
        if ((t & 63) >= s) incl += u;
    }
    __shared__ int ws[4];
    int lane = t & 63, w = t >> 6;
    if (lane == 63) ws[w] = incl;
    __syncthreads();
    int woff = 0;
    for (int j = 0; j < w; ++j) woff += ws[j];
    if (t < nb) boff[t] = woff + incl - v;
    if (t == 0) off[n] = E;
}

__global__ __launch_bounds__(256) void scan_kernel(const int* __restrict__ deg,
                                                   const int* __restrict__ boff,
                                                   int* __restrict__ off,
                                                   float* __restrict__ inv, int n) {
    int i = blockIdx.x * 256 + threadIdx.x;
    int v = (i < n) ? deg[i] : 0;
    int incl = v;
#pragma unroll
    for (int s = 1; s < 64; s <<= 1) {
        int u = __shfl_up(incl, s);
        if ((threadIdx.x & 63) >= s) incl += u;
    }
    __shared__ int ws[4];
    int lane = threadIdx.x & 63, w = threadIdx.x >> 6;
    if (lane == 63) ws[w] = incl;
    __syncthreads();
    int woff = 0;
    for (int j = 0; j < w; ++j) woff += ws[j];
    if (i < n) {
        off[i] = boff[blockIdx.x] + woff + incl - v;
        inv[i] = 1.0f / fmaxf((float)v, 1.0f);
    }
}

__global__ __launch_bounds__(256) void fill_kernel(const int* __restrict__ src,
                                                   const int* __restrict__ dst,
                                                   const int* __restrict__ off,
                                                   int* __restrict__ deg,
                                                   int* __restrict__ ssrc, int E) {
    int e = blockIdx.x * 256 + threadIdx.x;
    if (e >= E) return;
    int d = dst[e];
    int pos = off[d] + atomicSub(&deg[d], 1) - 1;
    ssrc[pos] = src[e];
}

// ---------------- one-shot converts (merged): x->bf16, W->bf16^T -----------
// blocks [0, XB) do xconv; blocks [XB, XB+WB) do wprep.

__global__ __launch_bounds__(256) void prep_all(
    const float* __restrict__ x, uint2* __restrict__ xb, int n4, int XB,
    const float* __restrict__ pre_W, const float* __restrict__ W1_l,
    const float* __restrict__ W1_r, const float* __restrict__ W2_l,
    const float* __restrict__ W2_r, const float* __restrict__ W3_l,
    const float* __restrict__ W3_r,
    unsigned short* __restrict__ WT0, unsigned short* __restrict__ WT1,
    unsigned short* __restrict__ WT2, unsigned short* __restrict__ WT3,
    unsigned short* __restrict__ WT4, unsigned short* __restrict__ WT5,
    unsigned short* __restrict__ WT6) {
    if (blockIdx.x < (unsigned)XB) {
        int i = blockIdx.x * 256 + threadIdx.x;
        if (i >= n4) return;
        float4 v = ((const float4*)x)[i];
        uint2 o;
        o.x = rne_bf16(v.x) | (rne_bf16(v.y) << 16);
        o.y = rne_bf16(v.z) | (rne_bf16(v.w) << 16);
        xb[i] = o;
        return;
    }
    int idx = (blockIdx.x - XB) * 256 + threadIdx.x;
    if (idx < 16384) {  // pre_W 128x128
        int k = idx >> 7, n = idx & 127;
        WT0[n * 128 + k] = (unsigned short)rne_bf16(pre_W[idx]);
        return;
    }
    idx -= 16384;
    if (idx < 32768) {  // W1_l 128x256
        int k = idx >> 8, n = idx & 255;
        WT1[n * 128 + k] = (unsigned short)rne_bf16(W1_l[idx]);
        return;
    }
    idx -= 32768;
    if (idx < 32768) {  // W1_r 128x256
        int k = idx >> 8, n = idx & 255;
        WT2[n * 128 + k] = (unsigned short)rne_bf16(W1_r[idx]);
        return;
    }
    idx -= 32768;
    if (idx < 65536) {  // W2_l 256x256
        int k = idx >> 8, n = idx & 255;
        WT3[n * 256 + k] = (unsigned short)rne_bf16(W2_l[idx]);
        return;
    }
    idx -= 65536;
    if (idx < 65536) {  // W2_r
        int k = idx >> 8, n = idx & 255;
        WT4[n * 256 + k] = (unsigned short)rne_bf16(W2_r[idx]);
        return;
    }
    idx -= 65536;
    if (idx < 65536) {  // W3_l
        int k = idx >> 8, n = idx & 255;
        WT5[n * 256 + k] = (unsigned short)rne_bf16(W3_l[idx]);
        return;
    }
    idx -= 65536;
    if (idx < 65536) {  // W3_r
        int k = idx >> 8, n = idx & 255;
        WT6[n * 256 + k] = (unsigned short)rne_bf16(W3_r[idx]);
    }
}

// ---------------- gather aggregation (R7 verbatim: best measured) ----------

template <int D>
__global__ __launch_bounds__(256) void gather_b(const unsigned short* __restrict__ h,
                                                const int* __restrict__ off,
                                                const int* __restrict__ ssrc,
                                                const float* __restrict__ inv,
                                                unsigned short* __restrict__ agg, int n) {
    int node = blockIdx.x * 4 + (threadIdx.x >> 6);
    if (node >= n) return;
    int lane = threadIdx.x & 63;
    int beg = off[node], end = off[node + 1];
    float sc = inv[node];

    if (D == 256) {
        const int half = lane >> 5;          // which edge of a pair
        const int sub  = lane & 31;          // 16B chunk within the row
        const unsigned short* col = h + (sub << 3);
        float a[8] = {0, 0, 0, 0, 0, 0, 0, 0};
        float b[8] = {0, 0, 0, 0, 0, 0, 0, 0};
        int k = beg;
        for (; k + 3 < end; k += 4) {        // 4 edges in flight
            int s0 = ssrc[k + half];
            int s1 = ssrc[k + 2 + half];
            uint4 u = *(const uint4*)(col + (size_t)s0 * 256);
            uint4 v = *(const uint4*)(col + (size_t)s1 * 256);
            a[0] += bf16_lo(u.x); a[1] += bf16_hi(u.x);
            a[2] += bf16_lo(u.y); a[3] += bf16_hi(u.y);
            a[4] += bf16_lo(u.z); a[5] += bf16_hi(u.z);
            a[6] += bf16_lo(u.w); a[7] += bf16_hi(u.w);
            b[0] += bf16_lo(v.x); b[1] += bf16_hi(v.x);
            b[2] += bf16_lo(v.y); b[3] += bf16_hi(v.y);
            b[4] += bf16_lo(v.z); b[5] += bf16_hi(v.z);
            b[6] += bf16_lo(v.w); b[7] += bf16_hi(v.w);
        }
        for (; k < end; k += 2) {            // 0..3 edges remain, predicated
            int e = k + half;
            if (e < end) {
                uint4 u = *(const uint4*)(col + (size_t)ssrc[e] * 256);
                a[0] += bf16_lo(u.x); a[1] += bf16_hi(u.x);
                a[2] += bf16_lo(u.y); a[3] += bf16_hi(u.y);
                a[4] += bf16_lo(u.z); a[5] += bf16_hi(u.z);
                a[6] += bf16_lo(u.w); a[7] += bf16_hi(u.w);
            }
        }
#pragma unroll
        for (int i = 0; i < 8; ++i) a[i] += b[i];
#pragma unroll
        for (int i = 0; i < 8; ++i) a[i] += __shfl_xor(a[i], 32);
        if (half == 0) {
#pragma unroll
            for (int i = 0; i < 8; ++i) a[i] *= sc;
            uint4 o;
            o.x = rne_bf16(a[0]) | (rne_bf16(a[1]) << 16);
            o.y = rne_bf16(a[2]) | (rne_bf16(a[3]) << 16);
            o.z = rne_bf16(a[4]) | (rne_bf16(a[5]) << 16);
            o.w = rne_bf16(a[6]) | (rne_bf16(a[7]) << 16);
            *(uint4*)(agg + (size_t)node * 256 + (sub << 3)) = o;
        }
    } else {  // D == 128
        const int q   = lane >> 4;           // which edge of a quad
        const int sub = lane & 15;           // 16B chunk within the row
        const unsigned short* col = h + (sub << 3);
        float a[8] = {0, 0, 0, 0, 0, 0, 0, 0};
        float b[8] = {0, 0, 0, 0, 0, 0, 0, 0};
        int k = beg;
        for (; k + 7 < end; k += 8) {        // 8 edges in flight
            int s0 = ssrc[k + q];
            int s1 = ssrc[k + 4 + q];
            uint4 u = *(const uint4*)(col + (size_t)s0 * 128);
            uint4 v = *(const uint4*)(col + (size_t)s1 * 128);
            a[0] += bf16_lo(u.x); a[1] += bf16_hi(u.x);
            a[2] += bf16_lo(u.y); a[3] += bf16_hi(u.y);
            a[4] += bf16_lo(u.z); a[5] += bf16_hi(u.z);
            a[6] += bf16_lo(u.w); a[7] += bf16_hi(u.w);
            b[0] += bf16_lo(v.x); b[1] += bf16_hi(v.x);
            b[2] += bf16_lo(v.y); b[3] += bf16_hi(v.y);
            b[4] += bf16_lo(v.z); b[5] += bf16_hi(v.z);
            b[6] += bf16_lo(v.w); b[7] += bf16_hi(v.w);
        }
        for (; k < end; k += 4) {            // 0..7 edges remain, predicated
            int e = k + q;
            if (e < end) {
                uint4 u = *(const uint4*)(col + (size_t)ssrc[e] * 128);
                a[0] += bf16_lo(u.x); a[1] += bf16_hi(u.x);
                a[2] += bf16_lo(u.y); a[3] += bf16_hi(u.y);
                a[4] += bf16_lo(u.z); a[5] += bf16_hi(u.z);
                a[6] += bf16_lo(u.w); a[7] += bf16_hi(u.w);
            }
        }
#pragma unroll
        for (int i = 0; i < 8; ++i) a[i] += b[i];
#pragma unroll
        for (int i = 0; i < 8; ++i) a[i] += __shfl_xor(a[i], 16);
#pragma unroll
        for (int i = 0; i < 8; ++i) a[i] += __shfl_xor(a[i], 32);
        if (q == 0) {
#pragma unroll
            for (int i = 0; i < 8; ++i) a[i] *= sc;
            uint4 o;
            o.x = rne_bf16(a[0]) | (rne_bf16(a[1]) << 16);
            o.y = rne_bf16(a[2]) | (rne_bf16(a[3]) << 16);
            o.z = rne_bf16(a[4]) | (rne_bf16(a[5]) << 16);
            o.w = rne_bf16(a[6]) | (rne_bf16(a[7]) << 16);
            *(uint4*)(agg + (size_t)node * 128 + (sub << 3)) = o;
        }
    }
}

// ---------------- legacy 128x128 GEMM (pre layer only) ---------------------
__global__ __launch_bounds__(256) void gemm_bt(
    const unsigned short* __restrict__ A1, const unsigned short* __restrict__ W1T,
    const float* __restrict__ bias, unsigned short* __restrict__ outb,
    int M, int K, int Nn) {
    __shared__ __align__(16) unsigned short As[128 * 64];
    __shared__ __align__(16) unsigned short Bs[128 * 64];

    const int t = threadIdx.x;
    const int lane = t & 63;
    const int w = t >> 6;
    const int wm = w >> 1, wn = w & 1;
    const int m0 = blockIdx.x * 128;
    const int n0 = blockIdx.y * 128;

    f32x4 acc[4][4];
#pragma unroll
    for (int i = 0; i < 4; ++i)
#pragma unroll
        for (int j = 0; j < 4; ++j) acc[i][j] = (f32x4){0.f, 0.f, 0.f, 0.f};

    for (int k0 = 0; k0 < K; k0 += 64) {
#pragma unroll
        for (int r = 0; r < 4; ++r) {
            int p = r * 256 + t;
            int row = p >> 3, slot = p & 7;
            int c = slot ^ (row & 7);
            int gm = m0 + row;
            if (gm >= M) gm = M - 1;
            uint4 va = *(const uint4*)(A1 + (size_t)gm * K + k0 + c * 8);
            uint4 vb = *(const uint4*)(W1T + (size_t)(n0 + row) * K + k0 + c * 8);
            *(uint4*)&As[(size_t)p * 8] = va;
            *(uint4*)&Bs[(size_t)p * 8] = vb;
        }
        __syncthreads();
#pragma unroll
        for (int kk = 0; kk < 2; ++kk) {
            short8 af[4], bfr[4];
            int ac = kk * 4 + (lane >> 4);
#pragma unroll
            for (int i = 0; i < 4; ++i) {
                int arow = wm * 64 + i * 16 + (lane & 15);
                af[i] = *(const short8*)&As[arow * 64 + ((ac ^ (arow & 7)) << 3)];
                int brow = wn * 64 + i * 16 + (lane & 15);
                bfr[i] = *(const short8*)&Bs[brow * 64 + ((ac ^ (brow & 7)) << 3)];
            }
#pragma unroll
            for (int mi = 0; mi < 4; ++mi)
#pragma unroll
                for (int ni = 0; ni < 4; ++ni)
                    acc[mi][ni] = __builtin_amdgcn_mfma_f32_16x16x32_bf16(
                        af[mi], bfr[ni], acc[mi][ni], 0, 0, 0);
        }
        __syncthreads();
    }

#pragma unroll
    for (int ni = 0; ni < 4; ++ni) {
        int n = n0 + wn * 64 + ni * 16 + (lane & 15);
        float bv = (bias != nullptr) ? bias[n] : 0.0f;
#pragma unroll
        for (int mi = 0; mi < 4; ++mi) {
            int mbase = m0 + wm * 64 + mi * 16 + ((lane >> 4) << 2);
#pragma unroll
            for (int r = 0; r < 4; ++r) {
                int m = mbase + r;
                if (m >= M) continue;
                outb[(size_t)m * Nn + n] = (unsigned short)rne_bf16(acc[mi][ni][r] + bv);
            }
        }
    }
}

// ---------------- wide GEMM: out = act(A1@W1T^T + bias + A2@W2T^T) ---------
// BM=128, BN=256 (Nn==256, grid.y==1 -> A read ONCE), BK=64, 512 thr 8 waves
// (2x4). Staging via global_load_lds(16B): linear LDS dest, source address
// pre-swizzled (LDS slot s of row r holds global chunk s^(r&7)); fragment
// ds_read side identical to legacy kernel. If outf != null: fused row
// L2-normalize (each row's 256 cols live in this block).
__global__ __launch_bounds__(512) void gemm_wide(
    const unsigned short* __restrict__ A1, const unsigned short* __restrict__ W1T,
    const unsigned short* __restrict__ A2, const unsigned short* __restrict__ W2T,
    const float* __restrict__ bias,
    unsigned short* __restrict__ outb, float* __restrict__ outf,
    int M, int K, int relu) {
    __shared__ __align__(16) unsigned short As[128 * 64];
    __shared__ __align__(16) unsigned short Bs[256 * 64];
    __shared__ float rs[128][4];

    const int t = threadIdx.x;
    const int lane = t & 63;
    const int w8 = t >> 6;                   // 0..7
    const int wm = w8 >> 2, wn = w8 & 3;     // 2 x 4 wave grid
    const int m0 = blockIdx.x * 128;

    f32x4 acc[4][4];
#pragma unroll
    for (int i = 0; i < 4; ++i)
#pragma unroll
        for (int j = 0; j < 4; ++j) acc[i][j] = (f32x4){0.f, 0.f, 0.f, 0.f};

    for (int pass = 0; pass < 2; ++pass) {
        const unsigned short* A = pass ? A2 : A1;
        const unsigned short* W = pass ? W2T : W1T;

        for (int k0 = 0; k0 < K; k0 += 64) {
            // ---- stage A-tile: 1024 chunks, wave w handles [w*128,(w+1)*128)
#pragma unroll
            for (int i = 0; i < 2; ++i) {
                int base = (w8 * 2 + i) * 64;
                int p = base + lane;
                int row = p >> 3, slot = p & 7;
                int c = slot ^ (row & 7);
                int gm = m0 + row;
                if (gm >= M) gm = M - 1;
                stage16(A + (size_t)gm * K + k0 + c * 8, &As[(size_t)base * 8], lane);
            }
            // ---- stage B-tile: 2048 chunks, wave w handles [w*256,(w+1)*256)
#pragma unroll
            for (int i = 0; i < 4; ++i) {
                int base = (w8 * 4 + i) * 64;
                int p = base + lane;
                int row = p >> 3, slot = p & 7;
                int c = slot ^ (row & 7);
                stage16(W + (size_t)row * K + k0 + c * 8, &Bs[(size_t)base * 8], lane);
            }
            __syncthreads();  // drains vmcnt (global_load_lds) before ds_read
#pragma unroll
            for (int kk = 0; kk < 2; ++kk) {
                short8 af[4], bfr[4];
                int ac = kk * 4 + (lane >> 4);
#pragma unroll
                for (int i = 0; i < 4; ++i) {
                    int arow = wm * 64 + i * 16 + (lane & 15);
                    af[i] = *(const short8*)&As[arow * 64 + ((ac ^ (arow & 7)) << 3)];
                    int brow = wn * 64 + i * 16 + (lane & 15);
                    bfr[i] = *(const short8*)&Bs[brow * 64 + ((ac ^ (brow & 7)) << 3)];
                }
#pragma unroll
                for (int mi = 0; mi < 4; ++mi)
#pragma unroll
                    for (int ni = 0; ni < 4; ++ni)
                        acc[mi][ni] = __builtin_amdgcn_mfma_f32_16x16x32_bf16(
                            af[mi], bfr[ni], acc[mi][ni], 0, 0, 0);
            }
            __syncthreads();
        }
    }

    // ---- epilogue. C/D layout: col(n)=lane&15, row(m)=(lane>>4)*4+reg ----
    if (outb) {  // bf16 out (+bias, +optional relu)
#pragma unroll
        for (int ni = 0; ni < 4; ++ni) {
            int n = wn * 64 + ni * 16 + (lane & 15);
            float bv = bias[n];
#pragma unroll
            for (int mi = 0; mi < 4; ++mi) {
                int mbase = m0 + wm * 64 + mi * 16 + ((lane >> 4) << 2);
#pragma unroll
                for (int r = 0; r < 4; ++r) {
                    int m = mbase + r;
                    if (m >= M) continue;
                    float v = acc[mi][ni][r] + bv;
                    if (relu) v = fmaxf(v, 0.0f);
                    outb[(size_t)m * 256 + n] = (unsigned short)rne_bf16(v);
                }
            }
        }
        return;
    }

    // fp32 out with fused L2 normalize
#pragma unroll
    for (int ni = 0; ni < 4; ++ni) {
        float bv = bias[wn * 64 + ni * 16 + (lane & 15)];
#pragma unroll
        for (int mi = 0; mi < 4; ++mi)
#pragma unroll
            for (int r = 0; r < 4; ++r) acc[mi][ni][r] += bv;
    }
    // per-row sum of squares: reduce 4 cols/thread, then across 16 lanes
#pragma unroll
    for (int mi = 0; mi < 4; ++mi) {
#pragma unroll
        for (int r = 0; r < 4; ++r) {
            float p = acc[mi][0][r] * acc[mi][0][r] + acc[mi][1][r] * acc[mi][1][r] +
                      acc[mi][2][r] * acc[mi][2][r] + acc[mi][3][r] * acc[mi][3][r];
            p += __shfl_xor(p, 1);
            p += __shfl_xor(p, 2);
            p += __shfl_xor(p, 4);
            p += __shfl_xor(p, 8);
            if ((lane & 15) == 0)
                rs[wm * 64 + mi * 16 + ((lane >> 4) << 2) + r][wn] = p;
        }
    }
    __syncthreads();
#pragma unroll
    for (int mi = 0; mi < 4; ++mi) {
        int mbase = m0 + wm * 64 + mi * 16 + ((lane >> 4) << 2);
        int lrow = wm * 64 + mi * 16 + ((lane >> 4) << 2);
#pragma unroll
        for (int r = 0; r < 4; ++r) {
            int m = mbase + r;
            if (m >= M) continue;
            float s = rs[lrow + r][0] + rs[lrow + r][1] + rs[lrow + r][2] + rs[lrow + r][3];
            float sc = 1.0f / fmaxf(sqrtf(s), 1e-12f);
#pragma unroll
            for (int ni = 0; ni < 4; ++ni) {
                int n = wn * 64 + ni * 16 + (lane & 15);
                outf[(size_t)m * 256 + n] = acc[mi][ni][r] * sc;
            }
        }
    }
}

extern "C" void kernel_launch(void* const* d_in, const int* in_sizes, int n_in,
                              void* d_out, int out_size, void* d_ws, size_t ws_size,
                              hipStream_t stream) {
    const int N = 50000;
    const int E = 800000;
    const int NB = (N + 255) / 256;

    const float* x     = (const float*)d_in[0];
    const int*   ei    = (const int*)d_in[1];
    const float* pre_W = (const float*)d_in[2];
    const float* pre_b = (const float*)d_in[3];
    const float* W1_l  = (const float*)d_in[4];
    const float* b1    = (const float*)d_in[5];
    const float* W1_r  = (const float*)d_in[6];
    const float* W2_l  = (const float*)d_in[7];
    const float* b2    = (const float*)d_in[8];
    const float* W2_r  = (const float*)d_in[9];
    const float* W3_l  = (const float*)d_in[10];
    const float* b3    = (const float*)d_in[11];
    const float* W3_r  = (const float*)d_in[12];
    float* out = (float*)d_out;

    const int* src = ei;
    const int* dst = ei + E;

    // ---- workspace layout ----
    int* deg  = (int*)d_ws;
    int* off  = deg + N;
    int* bsum = off + N + 1;
    int* boff = bsum + 256;
    int* ssrc = boff + 256;
    size_t int_words = (size_t)2 * N + 1 + 512 + E;
    int_words = (int_words + 3) & ~(size_t)3;  // 16B align

    float* inv = (float*)d_ws + int_words;
    unsigned short* us = (unsigned short*)(inv + N);

    unsigned short* xb  = us;                 us += (size_t)N * 128;
    unsigned short* WT0 = us;                 us += 16384;
    unsigned short* WT1 = us;                 us += 32768;
    unsigned short* WT2 = us;                 us += 32768;
    unsigned short* WT3 = us;                 us += 65536;
    unsigned short* WT4 = us;                 us += 65536;
    unsigned short* WT5 = us;                 us += 65536;
    unsigned short* WT6 = us;                 us += 65536;
    unsigned short* h0b   = us;               us += (size_t)N * 128;
    unsigned short* agg1b = us;               us += (size_t)N * 128;
    unsigned short* h1b   = us;               us += (size_t)N * 256;
    unsigned short* agg2b = us;               us += (size_t)N * 256;
    unsigned short* h2b   = us;               us += (size_t)N * 256;
    unsigned short* agg3b = us;               us += (size_t)N * 256;

    // ---- build CSR (counting sort by dst) ----
    hipMemsetAsync(deg, 0, (size_t)N * sizeof(int), stream);
    deg_kernel<<<(E + 255) / 256, 256, 0, stream>>>(dst, deg, E);
    bsum_kernel<<<NB, 256, 0, stream>>>(deg, bsum, N);
    bscan_kernel<<<1, 256, 0, stream>>>(bsum, boff, off, NB, N, E);
    scan_kernel<<<NB, 256, 0, stream>>>(deg, boff, off, inv, N);
    fill_kernel<<<(E + 255) / 256, 256, 0, stream>>>(src, dst, off, deg, ssrc, E);

    // ---- converts (merged) ----
    const int n4 = N * 128 / 4;
    const int XB = (n4 + 255) / 256;
    const int WB = (344064 + 255) / 256;
    prep_all<<<XB + WB, 256, 0, stream>>>(x, (uint2*)xb, n4, XB,
                                          pre_W, W1_l, W1_r, W2_l, W2_r, W3_l,
                                          W3_r, WT0, WT1, WT2, WT3, WT4, WT5, WT6);

    const int MT = (N + 127) / 128;  // 391
    const int AG = (N + 3) / 4;

    // ---- pre: h0 = x @ pre_W + pre_b ----
    gemm_bt<<<dim3(MT, 1), 256, 0, stream>>>(xb, WT0, pre_b, h0b, N, 128, 128);

    // ---- layer 1 ----
    gather_b<128><<<AG, 256, 0, stream>>>(h0b, off, ssrc, inv, agg1b, N);
    gemm_wide<<<MT, 512, 0, stream>>>(agg1b, WT1, h0b, WT2, b1, h1b, nullptr,
                                      N, 128, 1);

    // ---- layer 2 ----
    gather_b<256><<<AG, 256, 0, stream>>>(h1b, off, ssrc, inv, agg2b, N);
    gemm_wide<<<MT, 512, 0, stream>>>(agg2b, WT3, h1b, WT4, b2, h2b, nullptr,
                                      N, 256, 1);

    // ---- layer 3 (no relu), fp32 + fused L2 normalize into d_out ----
    gather_b<256><<<AG, 256, 0, stream>>>(h2b, off, ssrc, inv, agg3b, N);
    gemm_wide<<<MT, 512, 0, stream>>>(agg3b, WT5, h2b, WT6, b3, nullptr, out,
                                      N, 256, 0);
}